// Round 2
// baseline (827.635 us; speedup 1.0000x reference)
//
#include <hip/hip_runtime.h>
#include <hip/hip_bf16.h>

// Problem constants (shapes fixed by the reference)
#define SRCL 512
#define BSZ  16
#define SNTL 512
#define CDIM 512          // C == E == 512
#define KDIM 512
#define VOC  12000
#define EXTN 500
#define MROWS (SRCL*BSZ)  // 8192
#define TOTV (VOC+EXTN)   // 12500
#define NPAD 12032        // Wgen rows padded to 47*256 so GEMM2 has no bounds checks
#define LL_SIZE ((size_t)MROWS * TOTV)   // 102,400,000

typedef __attribute__((ext_vector_type(8))) short bf16x8;   // 8 bf16 (4 VGPRs)
typedef __attribute__((ext_vector_type(4))) float f32x4;

#define SBAR()   __builtin_amdgcn_s_barrier()
#define SCHED0() __builtin_amdgcn_sched_barrier(0)
#define LGKM0()  asm volatile("s_waitcnt lgkmcnt(0)" ::: "memory")
#define VM0()    asm volatile("s_waitcnt vmcnt(0)" ::: "memory")

__device__ __forceinline__ unsigned short f2bf(float x) {
  union { __hip_bfloat16 b; unsigned short u; } c;
  c.b = __float2bfloat16(x);
  return c.u;
}
__device__ __forceinline__ float bflo(unsigned int u) { return __uint_as_float(u << 16); }
__device__ __forceinline__ float bfhi(unsigned int u) { return __uint_as_float(u & 0xffff0000u); }

__device__ __forceinline__ void gload16(const void* g, void* l) {
  // async global->LDS, 16B per lane; LDS dest is wave-uniform base + lane*16
  __builtin_amdgcn_global_load_lds(
      (const __attribute__((address_space(1))) unsigned int*)g,
      (__attribute__((address_space(3))) unsigned int*)l, 16, 0, 0);
}

__device__ __forceinline__ float wred_max(float v) {
  for (int o = 32; o; o >>= 1) v = fmaxf(v, __shfl_down(v, o, 64));
  return v;
}
__device__ __forceinline__ float wred_sum(float v) {
  for (int o = 32; o; o >>= 1) v += __shfl_down(v, o, 64);
  return v;
}

// ---------------------------------------------------------------------------
// fp32 -> bf16 conversion (vectorized float4 -> ushort4)
// ---------------------------------------------------------------------------
__global__ void cvt_kernel(const float* __restrict__ co, const float* __restrict__ wt,
                           const float* __restrict__ wg,
                           unsigned short* __restrict__ cob,
                           unsigned short* __restrict__ wtb,
                           unsigned short* __restrict__ wgb) {
  const int stride = gridDim.x * blockDim.x;
  const int t0 = blockIdx.x * blockDim.x + threadIdx.x;
  for (int i = t0; i < MROWS*KDIM/4; i += stride) {
    const float4 v = ((const float4*)co)[i];
    ushort4 o; o.x = f2bf(v.x); o.y = f2bf(v.y); o.z = f2bf(v.z); o.w = f2bf(v.w);
    ((ushort4*)cob)[i] = o;
  }
  for (int i = t0; i < CDIM*KDIM/4; i += stride) {
    const float4 v = ((const float4*)wt)[i];
    ushort4 o; o.x = f2bf(v.x); o.y = f2bf(v.y); o.z = f2bf(v.z); o.w = f2bf(v.w);
    ((ushort4*)wtb)[i] = o;
  }
  for (int i = t0; i < NPAD*KDIM/4; i += stride) {
    float4 v = make_float4(0.f, 0.f, 0.f, 0.f);
    if (i < VOC*KDIM/4) v = ((const float4*)wg)[i];
    ushort4 o; o.x = f2bf(v.x); o.y = f2bf(v.y); o.z = f2bf(v.z); o.w = f2bf(v.w);
    ((ushort4*)wgb)[i] = o;
  }
}

// ---------------------------------------------------------------------------
// m97-structure bf16 MFMA GEMM (proven ~900 TF), used for the small EPI=0
// GEMM only (N=512 -> 256 blocks at 128x128; 256sq tiles would underfill).
// C = A(MxK) * B(NxK)^T; 128x128 tile, BK=32, global_load_lds w=16.
// ---------------------------------------------------------------------------
template<int EPI>
__launch_bounds__(256)
__global__ void gemm_bt(const short* __restrict__ A, const short* __restrict__ Bm,
                        const float* __restrict__ bias, void* __restrict__ outp) {
  __shared__ short As[128*32];
  __shared__ short Bs[128*32];
  const int tid  = threadIdx.x;
  const int wave = tid >> 6;
  const int lane = tid & 63;
  const int m0 = blockIdx.y * 128;
  const int n0 = blockIdx.x * 128;

  const int lrow = lane >> 2;          // 0..15
  const int lkof = (lane & 3) * 8;     // k element offset
  const size_t aG0 = (size_t)(m0 + wave*32 + lrow) * KDIM + lkof;
  const size_t aG1 = aG0 + (size_t)16 * KDIM;
  const size_t bG0 = (size_t)(n0 + wave*32 + lrow) * KDIM + lkof;
  const size_t bG1 = bG0 + (size_t)16 * KDIM;
  short* lA0 = As + wave*1024;  short* lA1 = lA0 + 512;
  short* lB0 = Bs + wave*1024;  short* lB1 = lB0 + 512;

  const int wm = wave & 1, wn = wave >> 1;
  const int quad = lane >> 4, r16 = lane & 15;
  const int aoff = (wm*64 + r16)*32 + quad*8;
  const int boff = (wn*64 + r16)*32 + quad*8;

  f32x4 acc[4][4];
#pragma unroll
  for (int i = 0; i < 4; ++i)
#pragma unroll
    for (int j = 0; j < 4; ++j) acc[i][j] = (f32x4){0.f,0.f,0.f,0.f};

  for (int kt = 0; kt < KDIM/32; ++kt) {
    const int kof = kt * 32;
    __syncthreads();
    gload16(A  + aG0 + kof, lA0);
    gload16(A  + aG1 + kof, lA1);
    gload16(Bm + bG0 + kof, lB0);
    gload16(Bm + bG1 + kof, lB1);
    __syncthreads();
    bf16x8 af[4], bf[4];
#pragma unroll
    for (int i = 0; i < 4; ++i) {
      af[i] = *(const bf16x8*)(As + aoff + i*512);
      bf[i] = *(const bf16x8*)(Bs + boff + i*512);
    }
#pragma unroll
    for (int mi = 0; mi < 4; ++mi)
#pragma unroll
      for (int ni = 0; ni < 4; ++ni)
        acc[mi][ni] = __builtin_amdgcn_mfma_f32_16x16x32_bf16(af[mi], bf[ni], acc[mi][ni], 0, 0, 0);
  }

#pragma unroll
  for (int mi = 0; mi < 4; ++mi) {
#pragma unroll
    for (int ni = 0; ni < 4; ++ni) {
#pragma unroll
      for (int r = 0; r < 4; ++r) {
        const int row = m0 + wm*64 + mi*16 + quad*4 + r;
        const int col = n0 + wn*64 + ni*16 + r16;
        float v = acc[mi][ni][r];
        if constexpr (EPI == 0) {
          v = tanhf(v + bias[col]);
          ((unsigned short*)outp)[(size_t)row * CDIM + col] = f2bf(v);
        } else if constexpr (EPI == 1) {
          v += (col < VOC) ? bias[col] : 0.f;
          ((float*)outp)[(size_t)row * TOTV + col] = v;
        } else {
          v += (col < VOC) ? bias[col] : 0.f;
          ((unsigned short*)outp)[(size_t)row * NPAD + col] = f2bf(v);
        }
      }
    }
  }
}

// ---------------------------------------------------------------------------
// 256x256 8-phase counted-vmcnt GEMM (m201 template port, plain HIP).
// C = A(MxK)*B(NxK)^T. BK=64, 8 waves (2M x 4N), per-wave out 128x64,
// LDS 128 KiB (2 dbuf x (A 256x64 + B 256x64) bf16, st_16x32 XOR-swizzled).
// Schedule per K-tile: 4 phases, each {ds_read frags || stage half-tiles ->
// s_barrier -> lgkmcnt(0) -> setprio(1) 16xMFMA setprio(0) -> s_barrier}.
// All 8 prefetch loads for tile kt+1 issue in phases 0-1 of kt; the single
// vmcnt(0) gate at end of phase 3 lands >=2 MFMA phases after last issue,
// so it drains without stalling and never blocks mid-loop (T4).
// Swizzle per rule #21: linear LDS dest, inverse-swizzled GLOBAL source,
// swizzled ds_read (swz(x) = x ^ (((x>>9)&1)<<5), involution).
// ---------------------------------------------------------------------------
template<int EPI>
__launch_bounds__(512, 2)
__global__ void gemm256(const short* __restrict__ A, const short* __restrict__ Bm,
                        const float* __restrict__ bias, void* __restrict__ outp) {
  __shared__ short lds[2][2][256*64];   // [dbuf][A=0/B=1][row][k], 128 KiB
  const int tid  = threadIdx.x;
  const int wave = tid >> 6;
  const int lane = tid & 63;
  const int m0 = blockIdx.y * 256;
  const int n0 = blockIdx.x * 256;

  // wave -> output quadrant: wm in {0,1} (128 rows), wn in {0..3} (64 cols)
  const int wm = wave >> 2;
  const int wn = wave & 3;
  const int quad = lane >> 4, r16 = lane & 15;

  // ---- staging geometry (all offsets in shorts) ----
  // thread t covers linear LDS bytes L = h*16384 + j*8192 + t*16; source is
  // the tile element at swz(L): row = L>>7, colbytes = (t&7)*16 ^ swzbit<<5.
  const int srow0 = wave*8 + (lane >> 3);
  const int scol  = ((((lane & 7) * 16) ^ (((lane >> 5) & 1) << 5)) >> 1);
  int goff[4];
#pragma unroll
  for (int h = 0; h < 2; ++h)
#pragma unroll
    for (int j = 0; j < 2; ++j)
      goff[h*2+j] = (h*128 + j*64 + srow0) * KDIM + scol;
  const short* Agp = A  + (size_t)m0 * KDIM;
  const short* Bgp = Bm + (size_t)n0 * KDIM;

  // ---- fragment-read geometry ----
  // frag(row, ks): bytes = row*128 + ks*64 + quad*16, swizzle-bit = (row>>2)&1
  // = (r16>>2)&1 (mi*16, wm*128 keep bit unchanged; no carry into bit 9).
  const int sx  = ((r16 >> 2) & 1) << 5;              // byte XOR
  const int kk0 = ((quad * 16) ^ sx) >> 1;            // shorts
  const int kk1 = ((64 + quad * 16) ^ sx) >> 1;
  const int arow = (wm*128 + r16) * 64;               // shorts
  const int brow = (wn*64  + r16) * 64;

  f32x4 acc[8][4];
#pragma unroll
  for (int i = 0; i < 8; ++i)
#pragma unroll
    for (int j = 0; j < 4; ++j) acc[i][j] = (f32x4){0.f,0.f,0.f,0.f};

  // ---- prologue: stage tile 0 (A halves 0,1 then B halves 0,1) ----
#pragma unroll
  for (int h = 0; h < 2; ++h)
#pragma unroll
    for (int j = 0; j < 2; ++j)
      gload16(Agp + goff[h*2+j], &lds[0][0][0] + h*8192 + j*4096 + wave*512);
#pragma unroll
  for (int h = 0; h < 2; ++h)
#pragma unroll
    for (int j = 0; j < 2; ++j)
      gload16(Bgp + goff[h*2+j], &lds[0][1][0] + h*8192 + j*4096 + wave*512);
  __syncthreads();   // prologue-only full drain (vmcnt(0) implicit)

  bf16x8 a0[4][2], b[4][2];
  int cur = 0;
#pragma unroll 2
  for (int kt = 0; kt < KDIM/64; ++kt) {
    const short* As_ = &lds[cur][0][0];
    const short* Bs_ = &lds[cur][1][0];
    short* An_ = &lds[cur^1][0][0];
    short* Bn_ = &lds[cur^1][1][0];
    const int kon = (kt + 1) * 64;
    const bool pf = (kt < KDIM/64 - 1);

    // ==== phase 0: read A(mi0-3), B(ni0-1); stage next A; MFMA mi0-3 x ni0-1
#pragma unroll
    for (int mi = 0; mi < 4; ++mi) {
      a0[mi][0] = *(const bf16x8*)(As_ + arow + mi*1024 + kk0);
      a0[mi][1] = *(const bf16x8*)(As_ + arow + mi*1024 + kk1);
    }
#pragma unroll
    for (int ni = 0; ni < 2; ++ni) {
      b[ni][0] = *(const bf16x8*)(Bs_ + brow + ni*1024 + kk0);
      b[ni][1] = *(const bf16x8*)(Bs_ + brow + ni*1024 + kk1);
    }
    if (pf) {
#pragma unroll
      for (int h = 0; h < 2; ++h)
#pragma unroll
        for (int j = 0; j < 2; ++j)
          gload16(Agp + kon + goff[h*2+j], An_ + h*8192 + j*4096 + wave*512);
    }
    SBAR(); LGKM0(); SCHED0();
    __builtin_amdgcn_s_setprio(1);
#pragma unroll
    for (int mi = 0; mi < 4; ++mi)
#pragma unroll
      for (int ni = 0; ni < 2; ++ni)
#pragma unroll
        for (int ks = 0; ks < 2; ++ks)
          acc[mi][ni] = __builtin_amdgcn_mfma_f32_16x16x32_bf16(a0[mi][ks], b[ni][ks], acc[mi][ni], 0, 0, 0);
    __builtin_amdgcn_s_setprio(0); SCHED0(); SBAR();

    // ==== phase 1: read B(ni2-3); stage next B; MFMA mi0-3 x ni2-3
#pragma unroll
    for (int ni = 2; ni < 4; ++ni) {
      b[ni][0] = *(const bf16x8*)(Bs_ + brow + ni*1024 + kk0);
      b[ni][1] = *(const bf16x8*)(Bs_ + brow + ni*1024 + kk1);
    }
    if (pf) {
#pragma unroll
      for (int h = 0; h < 2; ++h)
#pragma unroll
        for (int j = 0; j < 2; ++j)
          gload16(Bgp + kon + goff[h*2+j], Bn_ + h*8192 + j*4096 + wave*512);
    }
    SBAR(); LGKM0(); SCHED0();
    __builtin_amdgcn_s_setprio(1);
#pragma unroll
    for (int mi = 0; mi < 4; ++mi)
#pragma unroll
      for (int ni = 2; ni < 4; ++ni)
#pragma unroll
        for (int ks = 0; ks < 2; ++ks)
          acc[mi][ni] = __builtin_amdgcn_mfma_f32_16x16x32_bf16(a0[mi][ks], b[ni][ks], acc[mi][ni], 0, 0, 0);
    __builtin_amdgcn_s_setprio(0); SCHED0(); SBAR();

    // ==== phase 2: read A(mi4-7) (reuse regs); MFMA mi4-7 x ni2-3
#pragma unroll
    for (int mi = 0; mi < 4; ++mi) {
      a0[mi][0] = *(const bf16x8*)(As_ + arow + (mi+4)*1024 + kk0);
      a0[mi][1] = *(const bf16x8*)(As_ + arow + (mi+4)*1024 + kk1);
    }
    SBAR(); LGKM0(); SCHED0();
    __builtin_amdgcn_s_setprio(1);
#pragma unroll
    for (int mi = 0; mi < 4; ++mi)
#pragma unroll
      for (int ni = 2; ni < 4; ++ni)
#pragma unroll
        for (int ks = 0; ks < 2; ++ks)
          acc[mi+4][ni] = __builtin_amdgcn_mfma_f32_16x16x32_bf16(a0[mi][ks], b[ni][ks], acc[mi+4][ni], 0, 0, 0);
    __builtin_amdgcn_s_setprio(0); SCHED0(); SBAR();

    // ==== phase 3: MFMA mi4-7 x ni0-1 (b[0..1] live since phase 0); gate
    __builtin_amdgcn_s_setprio(1);
#pragma unroll
    for (int mi = 0; mi < 4; ++mi)
#pragma unroll
      for (int ni = 0; ni < 2; ++ni)
#pragma unroll
        for (int ks = 0; ks < 2; ++ks)
          acc[mi+4][ni] = __builtin_amdgcn_mfma_f32_16x16x32_bf16(a0[mi][ks], b[ni][ks], acc[mi+4][ni], 0, 0, 0);
    __builtin_amdgcn_s_setprio(0); SCHED0();
    VM0(); SCHED0(); SBAR();   // next tile fully staged; flip buffers
    cur ^= 1;
  }

  // epilogue; C/D layout: col = lane&15, row = quad*4 + reg (m89-verified)
#pragma unroll
  for (int mi = 0; mi < 8; ++mi) {
#pragma unroll
    for (int ni = 0; ni < 4; ++ni) {
#pragma unroll
      for (int r = 0; r < 4; ++r) {
        const int row = m0 + wm*128 + mi*16 + quad*4 + r;
        const int col = n0 + wn*64 + ni*16 + r16;
        float v = acc[mi][ni][r] + ((col < VOC) ? bias[col] : 0.f);
        if constexpr (EPI == 1) {
          ((float*)outp)[(size_t)row * TOTV + col] = v;       // pad cols overwritten later
        } else {
          ((unsigned short*)outp)[(size_t)row * NPAD + col] = f2bf(v);  // pad cols never read
        }
      }
    }
  }
}

// ---------------------------------------------------------------------------
// per-row: gates = softmax3(h.Wd + bd) (fused), softmax(logits)*gen_gate,
// scatter-add copy probs, log -> ll. One block (1024 thr) per row.
// BF16L=1: logits are bf16 ld=NPAD (in ws); BF16L=0: fp32 ld=TOTV (in d_out)
// ---------------------------------------------------------------------------
template<int BF16L>
__launch_bounds__(1024)
__global__ void finalize_kernel(const void* __restrict__ lg, float* __restrict__ out,
                                const __hip_bfloat16* __restrict__ hmat,
                                const float* __restrict__ Wd, const float* __restrict__ bd,
                                const int* __restrict__ copy_seq,
                                const float* __restrict__ align) {
  __shared__ __align__(16) float p[TOTV];
  __shared__ float scr[16];
  __shared__ float gscr[24];
  __shared__ float gv[3];
  const int m = blockIdx.x;      // = s*16 + b
  const int b = m & 15;
  const int tid = threadIdx.x;
  float* row = out + (size_t)m * TOTV;

  // gates: d_j = sum_c h[m,c]*Wd[j,c]; threads 0..511 each take one c
  {
    float d0 = 0.f, d1 = 0.f, d2 = 0.f;
    if (tid < CDIM) {
      const float hv = __bfloat162float(hmat[(size_t)m*CDIM + tid]);
      d0 = hv * Wd[tid];
      d1 = hv * Wd[CDIM + tid];
      d2 = hv * Wd[2*CDIM + tid];
    }
    d0 = wred_sum(d0); d1 = wred_sum(d1); d2 = wred_sum(d2);
    const int w = tid >> 6;
    if ((tid & 63) == 0 && w < 8) { gscr[w*3] = d0; gscr[w*3+1] = d1; gscr[w*3+2] = d2; }
  }
  __syncthreads();
  if (tid == 0) {
    float g0 = bd[0], g1 = bd[1], g2 = bd[2];
    for (int i = 0; i < 8; ++i) { g0 += gscr[i*3]; g1 += gscr[i*3+1]; g2 += gscr[i*3+2]; }
    const float mg = fmaxf(g0, fmaxf(g1, g2));
    const float e0 = __expf(g0-mg), e1 = __expf(g1-mg), e2 = __expf(g2-mg);
    const float inv3 = 1.f / (e0 + e1 + e2);
    gv[0] = e0*inv3; gv[1] = e1*inv3; gv[2] = e2*inv3;   // read after later barriers
  }

  // load logits into LDS (float4 ds_writes), tracking max
  float mx = -1e30f;
  if constexpr (BF16L) {
    const uint4* rowv = (const uint4*)((const unsigned short*)lg + (size_t)m * NPAD);
    for (int i = tid; i < VOC/8; i += 1024) {
      const uint4 q = rowv[i];
      float4 lo, hi;
      lo.x = bflo(q.x); lo.y = bfhi(q.x); lo.z = bflo(q.y); lo.w = bfhi(q.y);
      hi.x = bflo(q.z); hi.y = bfhi(q.z); hi.z = bflo(q.w); hi.w = bfhi(q.w);
      ((float4*)p)[i*2]   = lo;
      ((float4*)p)[i*2+1] = hi;
      mx = fmaxf(mx, fmaxf(fmaxf(fmaxf(lo.x,lo.y),fmaxf(lo.z,lo.w)),
                           fmaxf(fmaxf(hi.x,hi.y),fmaxf(hi.z,hi.w))));
    }
  } else {
    const float4* rowv = (const float4*)row;
    for (int i = tid; i < VOC/4; i += 1024) {
      const float4 v = rowv[i];
      ((float4*)p)[i] = v;
      mx = fmaxf(mx, fmaxf(fmaxf(v.x, v.y), fmaxf(v.z, v.w)));
    }
  }
  for (int i = VOC + tid; i < TOTV; i += 1024) p[i] = 0.f;

  mx = wred_max(mx);
  if ((tid & 63) == 0) scr[tid >> 6] = mx;
  __syncthreads();
  mx = scr[0];
#pragma unroll
  for (int i = 1; i < 16; ++i) mx = fmaxf(mx, scr[i]);
  __syncthreads();   // scr reuse

  float sm = 0.f;
  for (int i = tid; i < VOC; i += 1024) {
    const float e = __expf(p[i] - mx);
    p[i] = e;
    sm += e;
  }
  sm = wred_sum(sm);
  if ((tid & 63) == 0) scr[tid >> 6] = sm;
  __syncthreads();
  sm = scr[0];
#pragma unroll
  for (int i = 1; i < 16; ++i) sm += scr[i];

  const float gen  = gv[0];
  const float mapg = gv[1];
  const float cpg  = gv[2];
  const float scale = gen / sm;      // out_i = log(scale*(e_i + s_i/scale) + eps), exact algebra
  const float inv   = sm / gen;
  const float cw = cpg * inv, mw = mapg * inv;

  // scatter-add (1024 threads cover SNT=512 in one shot)
  if (tid < SNTL) {
    const float aw = align[(size_t)m * SNTL + tid];
    const int2 cs = *(const int2*)&copy_seq[(tid*BSZ + b)*2];
    atomicAdd(&p[cs.x], cw * aw);
    atomicAdd(&p[cs.y], mw * aw);
  }
  __syncthreads();

  for (int i = tid; i < TOTV/4; i += 1024) {
    const float4 v = ((const float4*)p)[i];
    float4 r;
    r.x = __logf(fmaf(v.x, scale, 1e-12f));
    r.y = __logf(fmaf(v.y, scale, 1e-12f));
    r.z = __logf(fmaf(v.z, scale, 1e-12f));
    r.w = __logf(fmaf(v.w, scale, 1e-12f));
    ((float4*)row)[i] = r;
  }
}

// ---------------------------------------------------------------------------
// arc_ll = log(arc_weight + 1e-12), float4-vectorized
// ---------------------------------------------------------------------------
__global__ void arc_kernel(const float4* __restrict__ arc, float4* __restrict__ out) {
  const int i = blockIdx.x * blockDim.x + threadIdx.x;
  if (i < (SRCL*BSZ*SRCL)/4) {
    const float4 v = arc[i];
    float4 r;
    r.x = __logf(v.x + 1e-12f);
    r.y = __logf(v.y + 1e-12f);
    r.z = __logf(v.z + 1e-12f);
    r.w = __logf(v.w + 1e-12f);
    out[i] = r;
  }
}

extern "C" void kernel_launch(void* const* d_in, const int* in_sizes, int n_in,
                              void* d_out, int out_size, void* d_ws, size_t ws_size,
                              hipStream_t stream) {
  (void)in_sizes; (void)n_in; (void)out_size;
  const float* align   = (const float*)d_in[0];
  const float* arc     = (const float*)d_in[1];
  const float* concept = (const float*)d_in[3];
  const int*   cseq    = (const int*)d_in[4];
  const float* Wt = (const float*)d_in[9];
  const float* bt = (const float*)d_in[10];
  const float* Wg = (const float*)d_in[11];
  const float* bg = (const float*)d_in[12];
  const float* Wd = (const float*)d_in[13];
  const float* bd = (const float*)d_in[14];
  float* out = (float*)d_out;

  // workspace layout
  unsigned short* cob = (unsigned short*)d_ws;          // 8192x512 bf16
  unsigned short* wtb = cob + (size_t)MROWS*KDIM;       // 512x512
  unsigned short* wgb = wtb + (size_t)CDIM*KDIM;        // 12032x512 (padded)
  unsigned short* hb  = wgb + (size_t)NPAD*KDIM;        // 8192x512
  unsigned short* logitsb = hb + (size_t)MROWS*KDIM;    // 8192x12032 bf16
  const size_t need = (size_t)((char*)(logitsb + (size_t)MROWS*NPAD) - (char*)d_ws);
  const bool use_bf16_logits = (ws_size >= need);   // ws_size constant per session

  cvt_kernel<<<2048, 256, 0, stream>>>(concept, Wt, Wg, cob, wtb, wgb);
  gemm_bt<0><<<dim3(CDIM/128, MROWS/128), 256, 0, stream>>>(
      (const short*)cob, (const short*)wtb, bt, (void*)hb);
  if (use_bf16_logits) {
    gemm256<2><<<dim3(NPAD/256, MROWS/256), 512, 0, stream>>>(
        (const short*)hb, (const short*)wgb, bg, (void*)logitsb);
    finalize_kernel<1><<<MROWS, 1024, 0, stream>>>(
        logitsb, out, (const __hip_bfloat16*)hb, Wd, bd, cseq, align);
  } else {
    gemm256<1><<<dim3(NPAD/256, MROWS/256), 512, 0, stream>>>(
        (const short*)hb, (const short*)wgb, bg, (void*)out);
    finalize_kernel<0><<<MROWS, 1024, 0, stream>>>(
        out, out, (const __hip_bfloat16*)hb, Wd, bd, cseq, align);
  }
  arc_kernel<<<4096, 256, 0, stream>>>((const float4*)arc, (float4*)(out + LL_SIZE));
}

// Round 3
// 819.901 us; speedup vs baseline: 1.0094x; 1.0094x over previous
//
#include <hip/hip_runtime.h>
#include <hip/hip_bf16.h>

// Problem constants (shapes fixed by the reference)
#define SRCL 512
#define BSZ  16
#define SNTL 512
#define CDIM 512          // C == E == 512
#define KDIM 512
#define VOC  12000
#define EXTN 500
#define MROWS (SRCL*BSZ)  // 8192
#define TOTV (VOC+EXTN)   // 12500
#define NPAD 12032        // Wgen rows padded to 94*128 so GEMM2 has no bounds checks
#define LL_SIZE ((size_t)MROWS * TOTV)   // 102,400,000

typedef __attribute__((ext_vector_type(8))) short bf16x8;   // 8 bf16 (4 VGPRs)
typedef __attribute__((ext_vector_type(4))) float f32x4;

__device__ __forceinline__ unsigned short f2bf(float x) {
  union { __hip_bfloat16 b; unsigned short u; } c;
  c.b = __float2bfloat16(x);
  return c.u;
}
__device__ __forceinline__ float bflo(unsigned int u) { return __uint_as_float(u << 16); }
__device__ __forceinline__ float bfhi(unsigned int u) { return __uint_as_float(u & 0xffff0000u); }

__device__ __forceinline__ void gload16(const void* g, void* l) {
  // async global->LDS, 16B per lane; LDS dest is wave-uniform base + lane*16
  __builtin_amdgcn_global_load_lds(
      (const __attribute__((address_space(1))) unsigned int*)g,
      (__attribute__((address_space(3))) unsigned int*)l, 16, 0, 0);
}

__device__ __forceinline__ float wred_max(float v) {
  for (int o = 32; o; o >>= 1) v = fmaxf(v, __shfl_down(v, o, 64));
  return v;
}
__device__ __forceinline__ float wred_sum(float v) {
  for (int o = 32; o; o >>= 1) v += __shfl_down(v, o, 64);
  return v;
}

// ---------------------------------------------------------------------------
// fp32 -> bf16 conversion (vectorized float4 -> ushort4)
// ---------------------------------------------------------------------------
__global__ void cvt_kernel(const float* __restrict__ co, const float* __restrict__ wt,
                           const float* __restrict__ wg,
                           unsigned short* __restrict__ cob,
                           unsigned short* __restrict__ wtb,
                           unsigned short* __restrict__ wgb) {
  const int stride = gridDim.x * blockDim.x;
  const int t0 = blockIdx.x * blockDim.x + threadIdx.x;
  for (int i = t0; i < MROWS*KDIM/4; i += stride) {
    const float4 v = ((const float4*)co)[i];
    ushort4 o; o.x = f2bf(v.x); o.y = f2bf(v.y); o.z = f2bf(v.z); o.w = f2bf(v.w);
    ((ushort4*)cob)[i] = o;
  }
  for (int i = t0; i < CDIM*KDIM/4; i += stride) {
    const float4 v = ((const float4*)wt)[i];
    ushort4 o; o.x = f2bf(v.x); o.y = f2bf(v.y); o.z = f2bf(v.z); o.w = f2bf(v.w);
    ((ushort4*)wtb)[i] = o;
  }
  for (int i = t0; i < NPAD*KDIM/4; i += stride) {
    float4 v = make_float4(0.f, 0.f, 0.f, 0.f);
    if (i < VOC*KDIM/4) v = ((const float4*)wg)[i];
    ushort4 o; o.x = f2bf(v.x); o.y = f2bf(v.y); o.z = f2bf(v.z); o.w = f2bf(v.w);
    ((ushort4*)wgb)[i] = o;
  }
}

// ---------------------------------------------------------------------------
// bf16 MFMA GEMM, C = A(MxK) * B(NxK)^T, m97 structure (best measured here):
// 128x128 tile, BK=32, global_load_lds w=16, 4 waves x (4x4) 16x16x32 MFMAs.
// EPI=0: h = tanh(acc + bias[col]) -> bf16, ld=CDIM
// EPI=1: logits = acc + bias[col<VOC] -> fp32 at row*TOTV+col (into d_out)
// EPI=2: logits = acc + bias[col<VOC] -> bf16 at row*NPAD+col (into ws)
// ---------------------------------------------------------------------------
template<int EPI>
__launch_bounds__(256)
__global__ void gemm_bt(const short* __restrict__ A, const short* __restrict__ Bm,
                        const float* __restrict__ bias, void* __restrict__ outp) {
  __shared__ short As[128*32];
  __shared__ short Bs[128*32];
  const int tid  = threadIdx.x;
  const int wave = tid >> 6;
  const int lane = tid & 63;
  const int m0 = blockIdx.y * 128;
  const int n0 = blockIdx.x * 128;

  // staging: wave w stages rows [32w, 32w+32) of both tiles; lane -> (row, k8)
  const int lrow = lane >> 2;          // 0..15
  const int lkof = (lane & 3) * 8;     // k element offset
  const size_t aG0 = (size_t)(m0 + wave*32 + lrow) * KDIM + lkof;
  const size_t aG1 = aG0 + (size_t)16 * KDIM;
  const size_t bG0 = (size_t)(n0 + wave*32 + lrow) * KDIM + lkof;
  const size_t bG1 = bG0 + (size_t)16 * KDIM;
  short* lA0 = As + wave*1024;  short* lA1 = lA0 + 512;
  short* lB0 = Bs + wave*1024;  short* lB1 = lB0 + 512;

  // compute: wave (wm,wn) owns a 64x64 quadrant = 4x4 subtiles of 16x16
  const int wm = wave & 1, wn = wave >> 1;
  const int quad = lane >> 4, r16 = lane & 15;
  const int aoff = (wm*64 + r16)*32 + quad*8;
  const int boff = (wn*64 + r16)*32 + quad*8;

  f32x4 acc[4][4];
#pragma unroll
  for (int i = 0; i < 4; ++i)
#pragma unroll
    for (int j = 0; j < 4; ++j) acc[i][j] = (f32x4){0.f,0.f,0.f,0.f};

  for (int kt = 0; kt < KDIM/32; ++kt) {
    const int kof = kt * 32;
    __syncthreads();                       // prev iter's LDS reads done
    gload16(A  + aG0 + kof, lA0);
    gload16(A  + aG1 + kof, lA1);
    gload16(Bm + bG0 + kof, lB0);
    gload16(Bm + bG1 + kof, lB1);
    __syncthreads();                       // staging visible
    bf16x8 af[4], bf[4];
#pragma unroll
    for (int i = 0; i < 4; ++i) {
      af[i] = *(const bf16x8*)(As + aoff + i*512);   // ds_read_b128
      bf[i] = *(const bf16x8*)(Bs + boff + i*512);
    }
#pragma unroll
    for (int mi = 0; mi < 4; ++mi)
#pragma unroll
      for (int ni = 0; ni < 4; ++ni)
        acc[mi][ni] = __builtin_amdgcn_mfma_f32_16x16x32_bf16(af[mi], bf[ni], acc[mi][ni], 0, 0, 0);
  }

  // epilogue; C/D layout: col = lane&15, row = quad*4 + reg  (m89-verified)
#pragma unroll
  for (int mi = 0; mi < 4; ++mi) {
#pragma unroll
    for (int ni = 0; ni < 4; ++ni) {
#pragma unroll
      for (int r = 0; r < 4; ++r) {
        const int row = m0 + wm*64 + mi*16 + quad*4 + r;
        const int col = n0 + wn*64 + ni*16 + r16;
        float v = acc[mi][ni][r];
        if constexpr (EPI == 0) {
          v = tanhf(v + bias[col]);
          ((unsigned short*)outp)[(size_t)row * CDIM + col] = f2bf(v);
        } else if constexpr (EPI == 1) {
          v += (col < VOC) ? bias[col] : 0.f;
          ((float*)outp)[(size_t)row * TOTV + col] = v;   // pad cols overwritten later
        } else {
          v += (col < VOC) ? bias[col] : 0.f;
          ((unsigned short*)outp)[(size_t)row * NPAD + col] = f2bf(v);  // pad cols never read
        }
      }
    }
  }
}

// ---------------------------------------------------------------------------
// per-row finalize, register-resident logits version:
//  - gates = softmax3(h.Wd + bd) fused (validated r1/r2)
//  - logits live in REGISTERS (<=16/thread); LDS p[] holds only the
//    zero-initialized scatter-add deltas -> halves LDS traffic vs staging
//  - out_i = log(scale*(e_i + delta_i) + eps), exact algebra as before
// one block (1024 thr = 16 waves) per row; ~50 KB LDS -> 2 blocks/CU
// BF16L=1: logits bf16 ld=NPAD (in ws); BF16L=0: fp32 ld=TOTV (in d_out)
// ---------------------------------------------------------------------------
template<int BF16L>
__launch_bounds__(1024)
__global__ void finalize_kernel(const void* __restrict__ lg, float* __restrict__ out,
                                const __hip_bfloat16* __restrict__ hmat,
                                const float* __restrict__ Wd, const float* __restrict__ bd,
                                const int* __restrict__ copy_seq,
                                const float* __restrict__ align) {
  __shared__ __align__(16) float p[TOTV];   // scatter-delta buffer
  __shared__ float scr[16];
  __shared__ float scr2[16];
  __shared__ float gscr[24];
  __shared__ float gv[3];
  const int m = blockIdx.x;      // = s*16 + b
  const int b = m & 15;
  const int tid = threadIdx.x;
  float* row = out + (size_t)m * TOTV;

  // zero the delta buffer (TOTV/4 = 3125 float4s)
  for (int i = tid; i < TOTV/4; i += 1024)
    ((float4*)p)[i] = make_float4(0.f, 0.f, 0.f, 0.f);

  // gates partials: d_j = sum_c h[m,c]*Wd[j,c]; threads 0..511 one c each
  {
    float d0 = 0.f, d1 = 0.f, d2 = 0.f;
    if (tid < CDIM) {
      const float hv = __bfloat162float(hmat[(size_t)m*CDIM + tid]);
      d0 = hv * Wd[tid];
      d1 = hv * Wd[CDIM + tid];
      d2 = hv * Wd[2*CDIM + tid];
    }
    d0 = wred_sum(d0); d1 = wred_sum(d1); d2 = wred_sum(d2);
    const int w = tid >> 6;
    if ((tid & 63) == 0 && w < 8) { gscr[w*3] = d0; gscr[w*3+1] = d1; gscr[w*3+2] = d2; }
  }

  // logits -> registers; thread t owns:
  //   BF16L=1: uint4 chunks t (elems 8t..8t+7) and t+1024 (if t<476)
  //   BF16L=0: float4 chunks t, t+1024, and t+2048 (if t<952)
  float v[16];
  float mx = -1e30f;
  bool hasB;
  if constexpr (BF16L) {
    const uint4* rowv = (const uint4*)((const unsigned short*)lg + (size_t)m * NPAD);
    const uint4 q0 = rowv[tid];                       // 1500 chunks > 1024
    v[0]=bflo(q0.x); v[1]=bfhi(q0.x); v[2]=bflo(q0.y); v[3]=bfhi(q0.y);
    v[4]=bflo(q0.z); v[5]=bfhi(q0.z); v[6]=bflo(q0.w); v[7]=bfhi(q0.w);
    hasB = tid < (VOC/8 - 1024);                      // 476
    if (hasB) {
      const uint4 q1 = rowv[tid + 1024];
      v[8]=bflo(q1.x);  v[9]=bfhi(q1.x);  v[10]=bflo(q1.y); v[11]=bfhi(q1.y);
      v[12]=bflo(q1.z); v[13]=bfhi(q1.z); v[14]=bflo(q1.w); v[15]=bfhi(q1.w);
#pragma unroll
      for (int j = 8; j < 16; ++j) mx = fmaxf(mx, v[j]);
    }
#pragma unroll
    for (int j = 0; j < 8; ++j) mx = fmaxf(mx, v[j]);
  } else {
    const float4* rowv = (const float4*)row;          // 3000 chunks
    const float4 f0 = rowv[tid];
    const float4 f1 = rowv[tid + 1024];
    v[0]=f0.x; v[1]=f0.y; v[2]=f0.z; v[3]=f0.w;
    v[4]=f1.x; v[5]=f1.y; v[6]=f1.z; v[7]=f1.w;
    hasB = tid < (VOC/4 - 2048);                      // 952
    if (hasB) {
      const float4 f2 = rowv[tid + 2048];
      v[8]=f2.x; v[9]=f2.y; v[10]=f2.z; v[11]=f2.w;
#pragma unroll
      for (int j = 8; j < 12; ++j) mx = fmaxf(mx, v[j]);
    }
#pragma unroll
    for (int j = 0; j < 8; ++j) mx = fmaxf(mx, v[j]);
  }

  mx = wred_max(mx);
  if ((tid & 63) == 0) scr[tid >> 6] = mx;
  __syncthreads();    // p zeroed, gscr + scr visible

  if (tid == 0) {
    float g0 = bd[0], g1 = bd[1], g2 = bd[2];
    for (int i = 0; i < 8; ++i) { g0 += gscr[i*3]; g1 += gscr[i*3+1]; g2 += gscr[i*3+2]; }
    const float mg = fmaxf(g0, fmaxf(g1, g2));
    const float e0 = __expf(g0-mg), e1 = __expf(g1-mg), e2 = __expf(g2-mg);
    const float inv3 = 1.f / (e0 + e1 + e2);
    gv[0] = e0*inv3; gv[1] = e1*inv3; gv[2] = e2*inv3;   // read after next barrier
  }

  mx = scr[0];
#pragma unroll
  for (int i = 1; i < 16; ++i) mx = fmaxf(mx, scr[i]);

  float sm = 0.f;
#pragma unroll
  for (int j = 0; j < 8; ++j) { v[j] = __expf(v[j] - mx); sm += v[j]; }
  if (hasB) {
    if constexpr (BF16L) {
#pragma unroll
      for (int j = 8; j < 16; ++j) { v[j] = __expf(v[j] - mx); sm += v[j]; }
    } else {
#pragma unroll
      for (int j = 8; j < 12; ++j) { v[j] = __expf(v[j] - mx); sm += v[j]; }
    }
  }
  sm = wred_sum(sm);
  if ((tid & 63) == 0) scr2[tid >> 6] = sm;
  __syncthreads();    // scr2 + gv visible
  sm = scr2[0];
#pragma unroll
  for (int i = 1; i < 16; ++i) sm += scr2[i];

  const float gen  = gv[0];
  const float mapg = gv[1];
  const float cpg  = gv[2];
  const float scale = gen / sm;      // out_i = log(scale*(e_i + s_i/scale) + eps)
  const float inv   = sm / gen;
  const float cw = cpg * inv, mw = mapg * inv;

  // scatter-add deltas (1024 threads cover SNT=512 in one shot)
  if (tid < SNTL) {
    const float aw = align[(size_t)m * SNTL + tid];
    const int2 cs = *(const int2*)&copy_seq[(tid*BSZ + b)*2];
    atomicAdd(&p[cs.x], cw * aw);
    atomicAdd(&p[cs.y], mw * aw);
  }
  __syncthreads();

  // output: e from registers, delta from LDS
  if constexpr (BF16L) {
    {
      const int c = tid;                       // float4 idx 2c, 2c+1
      const float4 d0 = ((const float4*)p)[2*c];
      const float4 d1 = ((const float4*)p)[2*c + 1];
      float4 r0, r1;
      r0.x = __logf(fmaf(v[0] + d0.x, scale, 1e-12f));
      r0.y = __logf(fmaf(v[1] + d0.y, scale, 1e-12f));
      r0.z = __logf(fmaf(v[2] + d0.z, scale, 1e-12f));
      r0.w = __logf(fmaf(v[3] + d0.w, scale, 1e-12f));
      r1.x = __logf(fmaf(v[4] + d1.x, scale, 1e-12f));
      r1.y = __logf(fmaf(v[5] + d1.y, scale, 1e-12f));
      r1.z = __logf(fmaf(v[6] + d1.z, scale, 1e-12f));
      r1.w = __logf(fmaf(v[7] + d1.w, scale, 1e-12f));
      ((float4*)row)[2*c]   = r0;
      ((float4*)row)[2*c+1] = r1;
    }
    if (hasB) {
      const int c = tid + 1024;
      const float4 d0 = ((const float4*)p)[2*c];
      const float4 d1 = ((const float4*)p)[2*c + 1];
      float4 r0, r1;
      r0.x = __logf(fmaf(v[8]  + d0.x, scale, 1e-12f));
      r0.y = __logf(fmaf(v[9]  + d0.y, scale, 1e-12f));
      r0.z = __logf(fmaf(v[10] + d0.z, scale, 1e-12f));
      r0.w = __logf(fmaf(v[11] + d0.w, scale, 1e-12f));
      r1.x = __logf(fmaf(v[12] + d1.x, scale, 1e-12f));
      r1.y = __logf(fmaf(v[13] + d1.y, scale, 1e-12f));
      r1.z = __logf(fmaf(v[14] + d1.z, scale, 1e-12f));
      r1.w = __logf(fmaf(v[15] + d1.w, scale, 1e-12f));
      ((float4*)row)[2*c]   = r0;
      ((float4*)row)[2*c+1] = r1;
    }
  } else {
#pragma unroll
    for (int cc = 0; cc < 3; ++cc) {
      if (cc == 2 && !hasB) break;
      const int c = tid + cc*1024;
      const float4 d = ((const float4*)p)[c];
      float4 r;
      r.x = __logf(fmaf(v[cc*4+0] + d.x, scale, 1e-12f));
      r.y = __logf(fmaf(v[cc*4+1] + d.y, scale, 1e-12f));
      r.z = __logf(fmaf(v[cc*4+2] + d.z, scale, 1e-12f));
      r.w = __logf(fmaf(v[cc*4+3] + d.w, scale, 1e-12f));
      ((float4*)row)[c] = r;
    }
  }
  // tail [VOC, TOTV): delta-only (e=0); 500 elems = 125 float4s
  if (tid < (TOTV - VOC)/4) {
    const int i = VOC/4 + tid;
    const float4 d = ((const float4*)p)[i];
    float4 r;
    r.x = __logf(fmaf(d.x, scale, 1e-12f));
    r.y = __logf(fmaf(d.y, scale, 1e-12f));
    r.z = __logf(fmaf(d.z, scale, 1e-12f));
    r.w = __logf(fmaf(d.w, scale, 1e-12f));
    ((float4*)row)[i] = r;
  }
}

// ---------------------------------------------------------------------------
// arc_ll = log(arc_weight + 1e-12), float4-vectorized
// ---------------------------------------------------------------------------
__global__ void arc_kernel(const float4* __restrict__ arc, float4* __restrict__ out) {
  const int i = blockIdx.x * blockDim.x + threadIdx.x;
  if (i < (SRCL*BSZ*SRCL)/4) {
    const float4 v = arc[i];
    float4 r;
    r.x = __logf(v.x + 1e-12f);
    r.y = __logf(v.y + 1e-12f);
    r.z = __logf(v.z + 1e-12f);
    r.w = __logf(v.w + 1e-12f);
    out[i] = r;
  }
}

extern "C" void kernel_launch(void* const* d_in, const int* in_sizes, int n_in,
                              void* d_out, int out_size, void* d_ws, size_t ws_size,
                              hipStream_t stream) {
  (void)in_sizes; (void)n_in; (void)out_size;
  const float* align   = (const float*)d_in[0];
  const float* arc     = (const float*)d_in[1];
  const float* concept = (const float*)d_in[3];
  const int*   cseq    = (const int*)d_in[4];
  const float* Wt = (const float*)d_in[9];
  const float* bt = (const float*)d_in[10];
  const float* Wg = (const float*)d_in[11];
  const float* bg = (const float*)d_in[12];
  const float* Wd = (const float*)d_in[13];
  const float* bd = (const float*)d_in[14];
  float* out = (float*)d_out;

  // workspace layout
  unsigned short* cob = (unsigned short*)d_ws;          // 8192x512 bf16
  unsigned short* wtb = cob + (size_t)MROWS*KDIM;       // 512x512
  unsigned short* wgb = wtb + (size_t)CDIM*KDIM;        // 12032x512 (padded)
  unsigned short* hb  = wgb + (size_t)NPAD*KDIM;        // 8192x512
  unsigned short* logitsb = hb + (size_t)MROWS*KDIM;    // 8192x12032 bf16
  const size_t need = (size_t)((char*)(logitsb + (size_t)MROWS*NPAD) - (char*)d_ws);
  const bool use_bf16_logits = (ws_size >= need);   // ws_size constant per session

  cvt_kernel<<<2048, 256, 0, stream>>>(concept, Wt, Wg, cob, wtb, wgb);
  gemm_bt<0><<<dim3(CDIM/128, MROWS/128), 256, 0, stream>>>(
      (const short*)cob, (const short*)wtb, bt, (void*)hb);
  if (use_bf16_logits) {
    gemm_bt<2><<<dim3(NPAD/128, MROWS/128), 256, 0, stream>>>(
        (const short*)hb, (const short*)wgb, bg, (void*)logitsb);
    finalize_kernel<1><<<MROWS, 1024, 0, stream>>>(
        logitsb, out, (const __hip_bfloat16*)hb, Wd, bd, cseq, align);
  } else {
    gemm_bt<1><<<dim3(NPAD/128, MROWS/128), 256, 0, stream>>>(
        (const short*)hb, (const short*)wgb, bg, (void*)out);
    finalize_kernel<0><<<MROWS, 1024, 0, stream>>>(
        out, out, (const __hip_bfloat16*)hb, Wd, bd, cseq, align);
  }
  arc_kernel<<<4096, 256, 0, stream>>>((const float4*)arc, (float4*)(out + LL_SIZE));
}

// Round 4
// 803.223 us; speedup vs baseline: 1.0304x; 1.0208x over previous
//
#include <hip/hip_runtime.h>
#include <hip/hip_bf16.h>

// Problem constants (shapes fixed by the reference)
#define SRCL 512
#define BSZ  16
#define SNTL 512
#define CDIM 512          // C == E == 512
#define KDIM 512
#define VOC  12000
#define EXTN 500
#define MROWS (SRCL*BSZ)  // 8192
#define TOTV (VOC+EXTN)   // 12500
#define NPAD 12032        // Wgen rows padded to 94*128 so GEMM2 has no bounds checks
#define LL_SIZE ((size_t)MROWS * TOTV)   // 102,400,000

typedef __attribute__((ext_vector_type(8))) short bf16x8;   // 8 bf16 (4 VGPRs)
typedef __attribute__((ext_vector_type(4))) float f32x4;

__device__ __forceinline__ unsigned short f2bf(float x) {
  union { __hip_bfloat16 b; unsigned short u; } c;
  c.b = __float2bfloat16(x);
  return c.u;
}
__device__ __forceinline__ float bflo(unsigned int u) { return __uint_as_float(u << 16); }
__device__ __forceinline__ float bfhi(unsigned int u) { return __uint_as_float(u & 0xffff0000u); }

__device__ __forceinline__ void gload16(const void* g, void* l) {
  // async global->LDS, 16B per lane; LDS dest is wave-uniform base + lane*16
  __builtin_amdgcn_global_load_lds(
      (const __attribute__((address_space(1))) unsigned int*)g,
      (__attribute__((address_space(3))) unsigned int*)l, 16, 0, 0);
}

__device__ __forceinline__ float wred_max(float v) {
  for (int o = 32; o; o >>= 1) v = fmaxf(v, __shfl_down(v, o, 64));
  return v;
}
__device__ __forceinline__ float wred_sum(float v) {
  for (int o = 32; o; o >>= 1) v += __shfl_down(v, o, 64);
  return v;
}

// ---------------------------------------------------------------------------
// fp32 -> bf16 conversion (vectorized float4 -> ushort4)
// ---------------------------------------------------------------------------
__global__ void cvt_kernel(const float* __restrict__ co, const float* __restrict__ wt,
                           const float* __restrict__ wg,
                           unsigned short* __restrict__ cob,
                           unsigned short* __restrict__ wtb,
                           unsigned short* __restrict__ wgb) {
  const int stride = gridDim.x * blockDim.x;
  const int t0 = blockIdx.x * blockDim.x + threadIdx.x;
  for (int i = t0; i < MROWS*KDIM/4; i += stride) {
    const float4 v = ((const float4*)co)[i];
    ushort4 o; o.x = f2bf(v.x); o.y = f2bf(v.y); o.z = f2bf(v.z); o.w = f2bf(v.w);
    ((ushort4*)cob)[i] = o;
  }
  for (int i = t0; i < CDIM*KDIM/4; i += stride) {
    const float4 v = ((const float4*)wt)[i];
    ushort4 o; o.x = f2bf(v.x); o.y = f2bf(v.y); o.z = f2bf(v.z); o.w = f2bf(v.w);
    ((ushort4*)wtb)[i] = o;
  }
  for (int i = t0; i < NPAD*KDIM/4; i += stride) {
    float4 v = make_float4(0.f, 0.f, 0.f, 0.f);
    if (i < VOC*KDIM/4) v = ((const float4*)wg)[i];
    ushort4 o; o.x = f2bf(v.x); o.y = f2bf(v.y); o.z = f2bf(v.z); o.w = f2bf(v.w);
    ((ushort4*)wgb)[i] = o;
  }
}

// ---------------------------------------------------------------------------
// bf16 MFMA GEMM, C = A(MxK) * B(NxK)^T, m97 structure:
// 128x128 tile, BK=32, global_load_lds w=16, 4 waves x (4x4) 16x16x32 MFMAs.
// EPI=0: h = tanh(acc + bias[col]) -> bf16, ld=CDIM
// EPI=1: logits = acc + bias[col<VOC] -> fp32 at row*TOTV+col (into d_out)
// EPI=2: logits = acc + bias[col<VOC] -> bf16 at row*NPAD+col (into ws)
// ---------------------------------------------------------------------------
template<int EPI>
__launch_bounds__(256)
__global__ void gemm_bt(const short* __restrict__ A, const short* __restrict__ Bm,
                        const float* __restrict__ bias, void* __restrict__ outp) {
  __shared__ short As[128*32];
  __shared__ short Bs[128*32];
  const int tid  = threadIdx.x;
  const int wave = tid >> 6;
  const int lane = tid & 63;
  const int m0 = blockIdx.y * 128;
  const int n0 = blockIdx.x * 128;

  // staging: wave w stages rows [32w, 32w+32) of both tiles; lane -> (row, k8)
  const int lrow = lane >> 2;          // 0..15
  const int lkof = (lane & 3) * 8;     // k element offset
  const size_t aG0 = (size_t)(m0 + wave*32 + lrow) * KDIM + lkof;
  const size_t aG1 = aG0 + (size_t)16 * KDIM;
  const size_t bG0 = (size_t)(n0 + wave*32 + lrow) * KDIM + lkof;
  const size_t bG1 = bG0 + (size_t)16 * KDIM;
  short* lA0 = As + wave*1024;  short* lA1 = lA0 + 512;
  short* lB0 = Bs + wave*1024;  short* lB1 = lB0 + 512;

  // compute: wave (wm,wn) owns a 64x64 quadrant = 4x4 subtiles of 16x16
  const int wm = wave & 1, wn = wave >> 1;
  const int quad = lane >> 4, r16 = lane & 15;
  const int aoff = (wm*64 + r16)*32 + quad*8;
  const int boff = (wn*64 + r16)*32 + quad*8;

  f32x4 acc[4][4];
#pragma unroll
  for (int i = 0; i < 4; ++i)
#pragma unroll
    for (int j = 0; j < 4; ++j) acc[i][j] = (f32x4){0.f,0.f,0.f,0.f};

  for (int kt = 0; kt < KDIM/32; ++kt) {
    const int kof = kt * 32;
    __syncthreads();                       // prev iter's LDS reads done
    gload16(A  + aG0 + kof, lA0);
    gload16(A  + aG1 + kof, lA1);
    gload16(Bm + bG0 + kof, lB0);
    gload16(Bm + bG1 + kof, lB1);
    __syncthreads();                       // staging visible
    bf16x8 af[4], bf[4];
#pragma unroll
    for (int i = 0; i < 4; ++i) {
      af[i] = *(const bf16x8*)(As + aoff + i*512);   // ds_read_b128
      bf[i] = *(const bf16x8*)(Bs + boff + i*512);
    }
#pragma unroll
    for (int mi = 0; mi < 4; ++mi)
#pragma unroll
      for (int ni = 0; ni < 4; ++ni)
        acc[mi][ni] = __builtin_amdgcn_mfma_f32_16x16x32_bf16(af[mi], bf[ni], acc[mi][ni], 0, 0, 0);
  }

  // epilogue; C/D layout: col = lane&15, row = quad*4 + reg  (m89-verified)
#pragma unroll
  for (int mi = 0; mi < 4; ++mi) {
#pragma unroll
    for (int ni = 0; ni < 4; ++ni) {
#pragma unroll
      for (int r = 0; r < 4; ++r) {
        const int row = m0 + wm*64 + mi*16 + quad*4 + r;
        const int col = n0 + wn*64 + ni*16 + r16;
        float v = acc[mi][ni][r];
        if constexpr (EPI == 0) {
          v = tanhf(v + bias[col]);
          ((unsigned short*)outp)[(size_t)row * CDIM + col] = f2bf(v);
        } else if constexpr (EPI == 1) {
          v += (col < VOC) ? bias[col] : 0.f;
          ((float*)outp)[(size_t)row * TOTV + col] = v;   // pad cols overwritten later
        } else {
          v += (col < VOC) ? bias[col] : 0.f;
          ((unsigned short*)outp)[(size_t)row * NPAD + col] = f2bf(v);  // pad cols never read
        }
      }
    }
  }
}

// ---------------------------------------------------------------------------
// gates = softmax(h @ W_div^T + b_div) per row; h read as bf16
// ---------------------------------------------------------------------------
__launch_bounds__(256)
__global__ void gates_kernel(const __hip_bfloat16* __restrict__ h,
                             const float* __restrict__ Wd, const float* __restrict__ bd,
                             float* __restrict__ gates) {
  __shared__ float scr[12];
  const int m = blockIdx.x;
  float d0 = 0.f, d1 = 0.f, d2 = 0.f;
  for (int c = threadIdx.x; c < CDIM; c += 256) {
    const float hv = __bfloat162float(h[(size_t)m*CDIM + c]);
    d0 += hv * Wd[c];
    d1 += hv * Wd[CDIM + c];
    d2 += hv * Wd[2*CDIM + c];
  }
  d0 = wred_sum(d0); d1 = wred_sum(d1); d2 = wred_sum(d2);
  const int w = threadIdx.x >> 6;
  if ((threadIdx.x & 63) == 0) { scr[w*3] = d0; scr[w*3+1] = d1; scr[w*3+2] = d2; }
  __syncthreads();
  if (threadIdx.x == 0) {
    float g0 = bd[0], g1 = bd[1], g2 = bd[2];
    for (int i = 0; i < 4; ++i) { g0 += scr[i*3]; g1 += scr[i*3+1]; g2 += scr[i*3+2]; }
    const float mx = fmaxf(g0, fmaxf(g1, g2));
    const float e0 = __expf(g0-mx), e1 = __expf(g1-mx), e2 = __expf(g2-mx);
    const float inv = 1.f / (e0 + e1 + e2);
    gates[m*3+0] = e0*inv; gates[m*3+1] = e1*inv; gates[m*3+2] = e2*inv;
  }
}

// ---------------------------------------------------------------------------
// per-row: softmax(logits)*gen_gate, scatter-add copy probs, log -> ll
// one block (1024 thr = 16 waves) per row; 50 KB LDS -> 2 blocks/CU = 32 w/CU
// BF16L=1: logits are bf16 ld=NPAD (in ws); BF16L=0: fp32 ld=TOTV (in d_out)
// ---------------------------------------------------------------------------
template<int BF16L>
__launch_bounds__(1024)
__global__ void finalize_kernel(const void* __restrict__ lg, float* __restrict__ out,
                                const float* __restrict__ gates,
                                const int* __restrict__ copy_seq,
                                const float* __restrict__ align) {
  __shared__ __align__(16) float p[TOTV];
  __shared__ float scr[16];
  const int m = blockIdx.x;      // = s*16 + b
  const int b = m & 15;
  const int tid = threadIdx.x;
  float* row = out + (size_t)m * TOTV;

  // load logits into LDS, tracking max
  float mx = -1e30f;
  if constexpr (BF16L) {
    const uint4* rowv = (const uint4*)((const unsigned short*)lg + (size_t)m * NPAD);
    for (int i = tid; i < VOC/8; i += 1024) {
      const uint4 q = rowv[i];
      const float v0 = bflo(q.x), v1 = bfhi(q.x), v2 = bflo(q.y), v3 = bfhi(q.y);
      const float v4 = bflo(q.z), v5 = bfhi(q.z), v6 = bflo(q.w), v7 = bfhi(q.w);
      const int base = i*8;
      p[base+0]=v0; p[base+1]=v1; p[base+2]=v2; p[base+3]=v3;
      p[base+4]=v4; p[base+5]=v5; p[base+6]=v6; p[base+7]=v7;
      mx = fmaxf(mx, fmaxf(fmaxf(fmaxf(v0,v1),fmaxf(v2,v3)), fmaxf(fmaxf(v4,v5),fmaxf(v6,v7))));
    }
  } else {
    const float4* rowv = (const float4*)row;
    for (int i = tid; i < VOC/4; i += 1024) {
      const float4 v = rowv[i];
      ((float4*)p)[i] = v;
      mx = fmaxf(mx, fmaxf(fmaxf(v.x, v.y), fmaxf(v.z, v.w)));
    }
  }
  for (int i = VOC + tid; i < TOTV; i += 1024) p[i] = 0.f;

  mx = wred_max(mx);
  if ((tid & 63) == 0) scr[tid >> 6] = mx;
  __syncthreads();
  mx = scr[0];
#pragma unroll
  for (int i = 1; i < 16; ++i) mx = fmaxf(mx, scr[i]);
  __syncthreads();   // scr reuse

  float sm = 0.f;
  for (int i = tid; i < VOC; i += 1024) {
    const float e = __expf(p[i] - mx);
    p[i] = e;
    sm += e;
  }
  sm = wred_sum(sm);
  if ((tid & 63) == 0) scr[tid >> 6] = sm;
  __syncthreads();
  sm = scr[0];
#pragma unroll
  for (int i = 1; i < 16; ++i) sm += scr[i];

  const float gen  = gates[m*3 + 0];
  const float mapg = gates[m*3 + 1];
  const float cpg  = gates[m*3 + 2];
  const float scale = gen / sm;      // out_i = log(scale*(e_i + s_i/scale) + eps), exact algebra
  const float inv   = sm / gen;
  const float cw = cpg * inv, mw = mapg * inv;

  // scatter-add (1024 threads cover SNT=512 in one shot)
  if (tid < SNTL) {
    const float aw = align[(size_t)m * SNTL + tid];
    const int2 cs = *(const int2*)&copy_seq[(tid*BSZ + b)*2];
    atomicAdd(&p[cs.x], cw * aw);
    atomicAdd(&p[cs.y], mw * aw);
  }
  __syncthreads();

  for (int i = tid; i < TOTV/4; i += 1024) {
    const float4 v = ((const float4*)p)[i];
    float4 r;
    r.x = __logf(fmaf(v.x, scale, 1e-12f));
    r.y = __logf(fmaf(v.y, scale, 1e-12f));
    r.z = __logf(fmaf(v.z, scale, 1e-12f));
    r.w = __logf(fmaf(v.w, scale, 1e-12f));
    ((float4*)row)[i] = r;
  }
}

// ---------------------------------------------------------------------------
// arc_ll = log(arc_weight + 1e-12), float4-vectorized
// ---------------------------------------------------------------------------
__global__ void arc_kernel(const float4* __restrict__ arc, float4* __restrict__ out) {
  const int i = blockIdx.x * blockDim.x + threadIdx.x;
  if (i < (SRCL*BSZ*SRCL)/4) {
    const float4 v = arc[i];
    float4 r;
    r.x = __logf(v.x + 1e-12f);
    r.y = __logf(v.y + 1e-12f);
    r.z = __logf(v.z + 1e-12f);
    r.w = __logf(v.w + 1e-12f);
    out[i] = r;
  }
}

extern "C" void kernel_launch(void* const* d_in, const int* in_sizes, int n_in,
                              void* d_out, int out_size, void* d_ws, size_t ws_size,
                              hipStream_t stream) {
  (void)in_sizes; (void)n_in; (void)out_size;
  const float* align   = (const float*)d_in[0];
  const float* arc     = (const float*)d_in[1];
  const float* concept = (const float*)d_in[3];
  const int*   cseq    = (const int*)d_in[4];
  const float* Wt = (const float*)d_in[9];
  const float* bt = (const float*)d_in[10];
  const float* Wg = (const float*)d_in[11];
  const float* bg = (const float*)d_in[12];
  const float* Wd = (const float*)d_in[13];
  const float* bd = (const float*)d_in[14];
  float* out = (float*)d_out;

  // workspace layout
  unsigned short* cob = (unsigned short*)d_ws;          // 8192x512 bf16
  unsigned short* wtb = cob + (size_t)MROWS*KDIM;       // 512x512
  unsigned short* wgb = wtb + (size_t)CDIM*KDIM;        // 12032x512 (padded)
  unsigned short* hb  = wgb + (size_t)NPAD*KDIM;        // 8192x512
  float* gates = (float*)(hb + (size_t)MROWS*KDIM);     // 8192x3
  unsigned short* logitsb = (unsigned short*)(gates + (size_t)MROWS*3);  // 8192x12032 bf16
  const size_t need = (size_t)((char*)(logitsb + (size_t)MROWS*NPAD) - (char*)d_ws);
  const bool use_bf16_logits = (ws_size >= need);   // ws_size constant per session

  cvt_kernel<<<2048, 256, 0, stream>>>(concept, Wt, Wg, cob, wtb, wgb);
  gemm_bt<0><<<dim3(CDIM/128, MROWS/128), 256, 0, stream>>>(
      (const short*)cob, (const short*)wtb, bt, (void*)hb);
  gates_kernel<<<MROWS, 256, 0, stream>>>((const __hip_bfloat16*)hb, Wd, bd, gates);
  if (use_bf16_logits) {
    gemm_bt<2><<<dim3(NPAD/128, MROWS/128), 256, 0, stream>>>(
        (const short*)hb, (const short*)wgb, bg, (void*)logitsb);
    finalize_kernel<1><<<MROWS, 1024, 0, stream>>>(logitsb, out, gates, cseq, align);
  } else {
    gemm_bt<1><<<dim3(NPAD/128, MROWS/128), 256, 0, stream>>>(
        (const short*)hb, (const short*)wgb, bg, (void*)out);
    finalize_kernel<0><<<MROWS, 1024, 0, stream>>>(out, out, gates, cseq, align);
  }
  arc_kernel<<<4096, 256, 0, stream>>>((const float4*)arc, (float4*)(out + LL_SIZE));
}